// Round 14
// baseline (475.455 us; speedup 1.0000x reference)
//
#include <hip/hip_runtime.h>
#include <math.h>

#define GH 256
#define GW 256

typedef float f4 __attribute__((ext_vector_type(4), aligned(4)));
typedef float f2 __attribute__((ext_vector_type(2), aligned(4)));

template<int CTRL, int RMASK>
__device__ __forceinline__ float dpp_add(float v) {
    int r = __builtin_amdgcn_update_dpp(0, __builtin_bit_cast(int, v), CTRL, RMASK, 0xF, true);
    return v + __builtin_bit_cast(float, r);
}
template<int CTRL, int RMASK>
__device__ __forceinline__ float dpp_max(float v) {
    int r = __builtin_amdgcn_update_dpp(0, __builtin_bit_cast(int, v), CTRL, RMASK, 0xF, true);
    return fmaxf(v, __builtin_bit_cast(float, r));
}
__device__ __forceinline__ float wave_sum63(float v) {
    v = dpp_add<0xB1, 0xF>(v);
    v = dpp_add<0x4E, 0xF>(v);
    v = dpp_add<0x141, 0xF>(v);
    v = dpp_add<0x140, 0xF>(v);
    v = dpp_add<0x142, 0xA>(v);
    v = dpp_add<0x143, 0xC>(v);
    return v;
}
__device__ __forceinline__ float wave_max63(float v) {
    v = dpp_max<0xB1, 0xF>(v);
    v = dpp_max<0x4E, 0xF>(v);
    v = dpp_max<0x141, 0xF>(v);
    v = dpp_max<0x140, 0xF>(v);
    v = dpp_max<0x142, 0xA>(v);
    v = dpp_max<0x143, 0xC>(v);
    return v;
}
__device__ __forceinline__ float rl63(float v) {
    return __builtin_bit_cast(float, __builtin_amdgcn_readlane(__builtin_bit_cast(int, v), 63));
}
__device__ __forceinline__ float frcp(float x)  { return __builtin_amdgcn_rcpf(x); }
__device__ __forceinline__ float frsq(float x)  { return __builtin_amdgcn_rsqf(x); }
__device__ __forceinline__ float fexp2(float x) { return __builtin_amdgcn_exp2f(x); }

// ---------- prep: per-cell {z, gx, gy, fr} with exact edge semantics ----------
__global__ __launch_bounds__(256) void prep_kernel(
    const float* __restrict__ z_grid,
    const float* __restrict__ friction,
    f4* __restrict__ tex)
{
    const int j = threadIdx.x;
    const int i = blockIdx.x;
    const int b = blockIdx.y;
    const float* __restrict__ z = z_grid + (size_t)b * (GH * GW);
    int ipu = (i < GH - 1) ? i + 1 : i;
    int imu = (i > 0) ? i - 1 : i;
    int jpv = (j < GW - 1) ? j + 1 : j;
    int jmv = (j > 0) ? j - 1 : j;
    float scu = (ipu - imu == 2) ? 0.5f : 1.0f;
    float scv = (jpv - jmv == 2) ? 0.5f : 1.0f;
    float gx = ((z[ipu * GW + j] - z[imu * GW + j]) * scu) * 10.0f;
    float gy = ((z[i * GW + jpv] - z[i * GW + jmv]) * scv) * 10.0f;
    f4 o;
    o.x = z[i * GW + j];
    o.y = gx;
    o.z = gy;
    o.w = friction[(size_t)b * (GH * GW) + i * GW + j];
    tex[(size_t)b * (GH * GW) + i * GW + j] = o;
}

// One step: 1 wave, 2 points/lane, no LDS, no barriers.
// PH<0: scalar store each step. PH in {0..3}: phased f4 store buffering.
#define STEP1W(TCUR, PH)                                                        \
do {                                                                            \
    f2 cc = *(const f2*)(ct + (TCUR) * 2);                                      \
    /* address phase + loads for both points (8 loads in flight) */             \
    float Pz_[2], l0_[2], l1_[2], l2_[2], du_[2], dv_[2];                       \
    f4 c00_[2], c01_[2], c10_[2], c11_[2];                                      \
    _Pragma("unroll")                                                           \
    for (int q = 0; q < 2; ++q) {                                               \
        float rx = R00 * ppx[q] + R01 * ppy[q] + R02 * ppz[q];                  \
        float ry = R10 * ppx[q] + R11 * ppy[q] + R12 * ppz[q];                  \
        float rz = R20 * ppx[q] + R21 * ppy[q] + R22 * ppz[q];                  \
        float Px = rx + X0, Py = ry + X1, Pz = rz + X2;                         \
        l0_[q] = Px - X0; l1_[q] = Py - X1; l2_[q] = Pz - X2;                   \
        Pz_[q] = Pz;                                                            \
        float u = fminf(fmaxf((Px + 12.8f) * 10.0f, 0.0f), 254.999f);           \
        float vv = fminf(fmaxf((Py + 12.8f) * 10.0f, 0.0f), 254.999f);          \
        int u0 = (int)u, v0 = (int)vv;                                          \
        du_[q] = u - (float)u0; dv_[q] = vv - (float)v0;                        \
        int idx = (u0 << 8) + v0;                                               \
        c00_[q] = tb[idx];                                                      \
        c01_[q] = tb[idx + 1];                                                  \
        c10_[q] = tb[idx + GW];                                                 \
        c11_[q] = tb[idx + GW + 1];                                             \
    }                                                                           \
    /* load-shadow work */                                                      \
    float cv = cc.x, cw = cc.y;                                                 \
    float half_ = (cw * 0.6f) * 0.5f;                                           \
    float vLs = cv - half_, vRs = cv + half_;                                   \
    float xp0_[2], xp1_[2], xp2_[2], ct0_[2], ct1_[2], ct2_[2];                 \
    _Pragma("unroll")                                                           \
    for (int q = 0; q < 2; ++q) {                                               \
        xp0_[q] = V0 + (W1 * l2_[q] - W2 * l1_[q]);                             \
        xp1_[q] = V1 + (W2 * l0_[q] - W0 * l2_[q]);                             \
        xp2_[q] = V2 + (W0 * l1_[q] - W1 * l0_[q]);                             \
        float cmd = isL[q] ? vLs : vRs;                                         \
        ct0_[q] = cmd * R00 - xp0_[q];  /* thrust = R col 0 (rsq dropped) */    \
        ct1_[q] = cmd * R10 - xp1_[q];                                          \
        ct2_[q] = cmd * R20 - xp2_[q];                                          \
    }                                                                           \
    /* physics per point (independent streams) */                               \
    float ic_[2], g0_[2], g1_[2], g2_[2], q0_[2], q1_[2], q2_[2], w_[2];        \
    float mic_[2], nx_[2], ny_[2], nz_[2], st0_[2], st1_[2], st2_[2];           \
    _Pragma("unroll")                                                           \
    for (int q = 0; q < 2; ++q) {                                               \
        float du = du_[q], dv = dv_[q];                                         \
        float w00 = (1.0f - du) * (1.0f - dv);                                  \
        float w10 = du * (1.0f - dv);                                           \
        float w01 = (1.0f - du) * dv;                                           \
        float w11 = du * dv;                                                    \
        f4 cb = c00_[q] * w00 + c10_[q] * w10 + c01_[q] * w01 + c11_[q] * w11;  \
        float zz = cb.x, gxs = cb.y, gys = cb.z, fr = cb.w;                     \
        float rn = frsq(gxs * gxs + gys * gys + 1.0f);                          \
        float nx = -gxs * rn, ny = -gys * rn, nzc = rn;                         \
        float dh = Pz_[q] - zz;                                                 \
        float ex = fexp2(dh * 14.426950408889634f);                             \
        float ic = frcp(1.0f + ex);                                             \
        float xdn = xp0_[q] * nx + xp1_[q] * ny + xp2_[q] * nzc;                \
        float mag = -(1000.0f * dh + 100.0f * xdn);                             \
        float mic = mag * ic;                                                   \
        float m_abs = fabsf(mic);                                               \
        float sl0 = fr * ct0_[q], sl1 = fr * ct1_[q], sl2 = fr * ct2_[q];       \
        float sdn = sl0 * nx + sl1 * ny + sl2 * nzc;                            \
        float st0 = sl0 - sdn * nx;                                             \
        float st1 = sl1 - sdn * ny;                                             \
        float st2 = sl2 - sdn * nzc;                                            \
        float g0 = mic * nx  + m_abs * st0;                                     \
        float g1 = mic * ny  + m_abs * st1;                                     \
        float g2 = mic * nzc + m_abs * st2;                                     \
        ic_[q] = ic; mic_[q] = mic;                                             \
        nx_[q] = nx; ny_[q] = ny; nz_[q] = nzc;                                 \
        st0_[q] = st0; st1_[q] = st1; st2_[q] = st2;                            \
        g0_[q] = g0; g1_[q] = g1; g2_[q] = g2;                                  \
        q0_[q] = l1_[q] * g2 - l2_[q] * g1;                                     \
        q1_[q] = l2_[q] * g0 - l0_[q] * g2;                                     \
        q2_[q] = l0_[q] * g1 - l1_[q] * g0;                                     \
        float stm = fmaxf(fmaxf(fabsf(st0), fabsf(st1)), fabsf(st2));           \
        w_[q] = fmaxf(stm, 1.0f) * m_abs;                                       \
    }                                                                           \
    /* pre-add pair, then 7 sums + 1 max DPP chains, readlane broadcast */      \
    float sic = rl63(wave_sum63(ic_[0] + ic_[1]));                              \
    float rg0 = rl63(wave_sum63(g0_[0] + g0_[1]));                              \
    float rg1 = rl63(wave_sum63(g1_[0] + g1_[1]));                              \
    float rg2 = rl63(wave_sum63(g2_[0] + g2_[1]));                              \
    float rq0 = rl63(wave_sum63(q0_[0] + q0_[1]));                              \
    float rq1 = rl63(wave_sum63(q1_[0] + q1_[1]));                              \
    float rq2 = rl63(wave_sum63(q2_[0] + q2_[1]));                              \
    float rw  = rl63(wave_max63(fmaxf(w_[0], w_[1])));                          \
    float rsic = frcp(sic);                                                     \
    float FT0, FT1, FT2, TQ0, TQ1, TQ2;                                         \
    if (rw <= 391.0f * sic) {                                                   \
        FT0 = rg0 * rsic; FT1 = rg1 * rsic; FT2 = rg2 * rsic;                   \
        TQ0 = rq0 * rsic; TQ1 = rq1 * rsic; TQ2 = rq2 * rsic;                   \
    } else {                                                                    \
        float S0a = 0.f, S1a = 0.f, S2a = 0.f, U0a = 0.f, U1a = 0.f, U2a = 0.f; \
        _Pragma("unroll")                                                       \
        for (int q = 0; q < 2; ++q) {                                           \
            float s = mic_[q] * rsic;                                           \
            float Fr0 = fminf(fmaxf(s * nx_[q], -392.0f), 392.0f);              \
            float Fr1 = fminf(fmaxf(s * ny_[q], -392.0f), 392.0f);              \
            float Fr2 = fminf(fmaxf(s * nz_[q], -392.0f), 392.0f);              \
            float Nm = __builtin_amdgcn_sqrtf(Fr0 * Fr0 + Fr1 * Fr1 + Fr2 * Fr2);\
            float Ff0 = fminf(fmaxf(Nm * st0_[q], -392.0f), 392.0f);            \
            float Ff1 = fminf(fmaxf(Nm * st1_[q], -392.0f), 392.0f);            \
            float Ff2 = fminf(fmaxf(Nm * st2_[q], -392.0f), 392.0f);            \
            float S0 = Fr0 + Ff0, S1 = Fr1 + Ff1, S2 = Fr2 + Ff2;               \
            S0a += S0; S1a += S1; S2a += S2;                                    \
            U0a += l1_[q] * S2 - l2_[q] * S1;                                   \
            U1a += l2_[q] * S0 - l0_[q] * S2;                                   \
            U2a += l0_[q] * S1 - l1_[q] * S0;                                   \
        }                                                                       \
        FT0 = rl63(wave_sum63(S0a));                                            \
        FT1 = rl63(wave_sum63(S1a));                                            \
        FT2 = rl63(wave_sum63(S2a));                                            \
        TQ0 = rl63(wave_sum63(U0a));                                            \
        TQ1 = rl63(wave_sum63(U1a));                                            \
        TQ2 = rl63(wave_sum63(U2a));                                            \
    }                                                                           \
    float od0 = fminf(fmaxf(TQ0 * i00 + TQ1 * i01 + TQ2 * i02, -2.0f), 2.0f);   \
    float od1 = fminf(fmaxf(TQ0 * i01 + TQ1 * i11 + TQ2 * i12, -2.0f), 2.0f);   \
    float od2 = fminf(fmaxf(TQ0 * i02 + TQ1 * i12 + TQ2 * i22, -2.0f), 2.0f);   \
    V0 += (FT0 * 0.025f) * 0.01f;                                               \
    V1 += (FT1 * 0.025f) * 0.01f;                                               \
    V2 += ((-392.0f + FT2) * 0.025f) * 0.01f;                                   \
    X0 += V0 * 0.01f; X1 += V1 * 0.01f; X2 += V2 * 0.01f;                       \
    W0 += od0 * 0.01f; W1 += od1 * 0.01f; W2 += od2 * 0.01f;                    \
    if (PH < 0) {                                                               \
        if (lane == 0) {                                                        \
            ob[(TCUR) * 3 + 0] = X0;                                            \
            ob[(TCUR) * 3 + 1] = X1;                                            \
            ob[(TCUR) * 3 + 2] = X2;                                            \
        }                                                                       \
    } else if (PH == 0) { sb0.x = X0; sb0.y = X1; sb0.z = X2; }                 \
    else if (PH == 1) { sb0.w = X0; sb1.x = X1; sb1.y = X2; }                   \
    else if (PH == 2) { sb1.z = X0; sb1.w = X1; sb2.x = X2; }                   \
    else {                                                                      \
        sb2.y = X0; sb2.z = X1; sb2.w = X2;                                     \
        if (lane == 0) {                                                        \
            f4* op = (f4*)(ob + ((TCUR) - 3) * 3);                              \
            op[0] = sb0; op[1] = sb1; op[2] = sb2;                              \
        }                                                                       \
    }                                                                           \
    /* polynomial Rodrigues (R7-validated) */                                   \
    float th2s = W0 * W0 + W1 * W1 + W2 * W2;                                   \
    float a2 = th2s * 1e-4f;                                                    \
    float s1 = 0.01f - a2 * (0.01f / 6.0f);                                     \
    float c2 = 5e-5f - a2 * (1e-4f / 24.0f);                                    \
    float w01p = W0 * W1, w02p = W0 * W2, w12p = W1 * W2;                       \
    float A00 = 1.0f - c2 * (W1 * W1 + W2 * W2);                                \
    float A11 = 1.0f - c2 * (W0 * W0 + W2 * W2);                                \
    float A22 = 1.0f - c2 * (W0 * W0 + W1 * W1);                                \
    float A01 = c2 * w01p - s1 * W2;                                            \
    float A10 = c2 * w01p + s1 * W2;                                            \
    float A02 = c2 * w02p + s1 * W1;                                            \
    float A20 = c2 * w02p - s1 * W1;                                            \
    float A12 = c2 * w12p - s1 * W0;                                            \
    float A21 = c2 * w12p + s1 * W0;                                            \
    float N00 = R00 * A00 + R01 * A10 + R02 * A20;                              \
    float N01 = R00 * A01 + R01 * A11 + R02 * A21;                              \
    float N02 = R00 * A02 + R01 * A12 + R02 * A22;                              \
    float N10 = R10 * A00 + R11 * A10 + R12 * A20;                              \
    float N11 = R10 * A01 + R11 * A11 + R12 * A21;                              \
    float N12 = R10 * A02 + R11 * A12 + R12 * A22;                              \
    float N20 = R20 * A00 + R21 * A10 + R22 * A20;                              \
    float N21 = R20 * A01 + R21 * A11 + R22 * A21;                              \
    float N22 = R20 * A02 + R21 * A12 + R22 * A22;                              \
    R00 = N00; R01 = N01; R02 = N02;                                            \
    R10 = N10; R11 = N11; R12 = N12;                                            \
    R20 = N20; R21 = N21; R22 = N22;                                            \
} while (0)

// ---------- main sim kernel: 1 wave, 2 pts/lane, no LDS, no barriers ----------
__global__ __launch_bounds__(64) void dphys_kernel(
    const f4* __restrict__ tex,
    const float* __restrict__ controls,
    const float* __restrict__ robot_points,
    const float* __restrict__ x0,
    const float* __restrict__ xd0,
    const float* __restrict__ R0,
    const float* __restrict__ omega0,
    float* __restrict__ out,
    int T)
{
    const int b = blockIdx.x;
    const int lane = threadIdx.x;

    const f4* __restrict__ tb = tex + (size_t)b * (GH * GW);
    const float* __restrict__ ct = controls + (size_t)b * (T * 2);
    float* __restrict__ ob = out + (size_t)b * (T * 3);

    float ppx[2], ppy[2], ppz[2];
    bool isL[2];
    #pragma unroll
    for (int q = 0; q < 2; ++q) {
        int n = lane + q * 64;
        ppx[q] = robot_points[n * 3 + 0];
        ppy[q] = robot_points[n * 3 + 1];
        ppz[q] = robot_points[n * 3 + 2];
        isL[q] = (ppy[q] < 0.0f);
    }

    // inertia (one-time): pre-add pair, DPP, readlane; adjugate inverse in double
    float I6[6];
    {
        float s[6] = {0, 0, 0, 0, 0, 0};
        #pragma unroll
        for (int q = 0; q < 2; ++q) {
            float X = ppx[q], Y = ppy[q], Z = ppz[q];
            s[0] += Y * Y + Z * Z;
            s[1] += X * X + Z * Z;
            s[2] += X * X + Y * Y;
            s[3] += X * Y;
            s[4] += X * Z;
            s[5] += Y * Z;
        }
        #pragma unroll
        for (int k = 0; k < 6; ++k) I6[k] = rl63(wave_sum63(s[k]));
    }
    const float mp = 0.3125f;  // MASS/N exact
    {
        double a = mp * I6[0], bb = mp * I6[1], c = mp * I6[2];
        double d = -(mp * I6[3]), e = -(mp * I6[4]), f = -(mp * I6[5]);
        double C00 = bb * c - f * f, C01 = e * f - d * c, C02 = d * f - bb * e;
        double C11 = a * c - e * e, C12 = d * e - a * f, C22 = a * bb - d * d;
        double idet = 1.0 / (a * C00 + d * C01 + e * C02);
        I6[0] = (float)(C00 * idet); I6[1] = (float)(C11 * idet); I6[2] = (float)(C22 * idet);
        I6[3] = (float)(C01 * idet); I6[4] = (float)(C02 * idet); I6[5] = (float)(C12 * idet);
    }
    const float i00 = I6[0], i11 = I6[1], i22 = I6[2];
    const float i01 = I6[3], i02 = I6[4], i12 = I6[5];

    float X0 = x0[b * 3 + 0], X1 = x0[b * 3 + 1], X2 = x0[b * 3 + 2];
    float V0 = xd0[b * 3 + 0], V1 = xd0[b * 3 + 1], V2 = xd0[b * 3 + 2];
    float W0 = omega0[b * 3 + 0], W1 = omega0[b * 3 + 1], W2 = omega0[b * 3 + 2];
    float R00 = R0[b * 9 + 0], R01 = R0[b * 9 + 1], R02 = R0[b * 9 + 2];
    float R10 = R0[b * 9 + 3], R11 = R0[b * 9 + 4], R12 = R0[b * 9 + 5];
    float R20 = R0[b * 9 + 6], R21 = R0[b * 9 + 7], R22 = R0[b * 9 + 8];

    f4 sb0, sb1, sb2;   // 4-step output buffer

    int t = 0;
    for (; t + 3 < T; t += 4) {
        STEP1W(t + 0, 0);
        STEP1W(t + 1, 1);
        STEP1W(t + 2, 2);
        STEP1W(t + 3, 3);
    }
    for (; t < T; ++t) {
        STEP1W(t, -1);
    }
}

// ---------- fallback (no-workspace path): single-wave on raw grids ----------
__global__ __launch_bounds__(64) void dphys_kernel_fb(
    const float* __restrict__ z_grid,
    const float* __restrict__ friction,
    const float* __restrict__ controls,
    const float* __restrict__ robot_points,
    const float* __restrict__ x0,
    const float* __restrict__ xd0,
    const float* __restrict__ R0,
    const float* __restrict__ omega0,
    float* __restrict__ out,
    int T)
{
    const int b = blockIdx.x;
    const int lane = threadIdx.x;
    const float* __restrict__ zg = z_grid + (size_t)b * (GH * GW);
    const float* __restrict__ fg = friction + (size_t)b * (GH * GW);
    const float* __restrict__ ct = controls + (size_t)b * (T * 2);
    float* __restrict__ ob = out + (size_t)b * (T * 3);

    float ppx[2], ppy[2], ppz[2];
    bool isL[2];
    #pragma unroll
    for (int q = 0; q < 2; ++q) {
        int n = lane + q * 64;
        ppx[q] = robot_points[n * 3 + 0];
        ppy[q] = robot_points[n * 3 + 1];
        ppz[q] = robot_points[n * 3 + 2];
        isL[q] = (ppy[q] < 0.0f);
    }

    float I6[6];
    {
        float s[6] = {0, 0, 0, 0, 0, 0};
        #pragma unroll
        for (int q = 0; q < 2; ++q) {
            float X = ppx[q], Y = ppy[q], Z = ppz[q];
            s[0] += Y * Y + Z * Z;
            s[1] += X * X + Z * Z;
            s[2] += X * X + Y * Y;
            s[3] += X * Y;
            s[4] += X * Z;
            s[5] += Y * Z;
        }
        #pragma unroll
        for (int k = 0; k < 6; ++k) I6[k] = rl63(wave_sum63(s[k]));
    }
    const float mp = 0.3125f;
    {
        double a = mp * I6[0], bb = mp * I6[1], c = mp * I6[2];
        double d = -(mp * I6[3]), e = -(mp * I6[4]), f = -(mp * I6[5]);
        double C00 = bb * c - f * f, C01 = e * f - d * c, C02 = d * f - bb * e;
        double C11 = a * c - e * e, C12 = d * e - a * f, C22 = a * bb - d * d;
        double idet = 1.0 / (a * C00 + d * C01 + e * C02);
        I6[0] = (float)(C00 * idet); I6[1] = (float)(C11 * idet); I6[2] = (float)(C22 * idet);
        I6[3] = (float)(C01 * idet); I6[4] = (float)(C02 * idet); I6[5] = (float)(C12 * idet);
    }
    const float i00 = I6[0], i11 = I6[1], i22 = I6[2];
    const float i01 = I6[3], i02 = I6[4], i12 = I6[5];

    float X0 = x0[b * 3 + 0], X1 = x0[b * 3 + 1], X2 = x0[b * 3 + 2];
    float V0 = xd0[b * 3 + 0], V1 = xd0[b * 3 + 1], V2 = xd0[b * 3 + 2];
    float W0 = omega0[b * 3 + 0], W1 = omega0[b * 3 + 1], W2 = omega0[b * 3 + 2];
    float R00 = R0[b * 9 + 0], R01 = R0[b * 9 + 1], R02 = R0[b * 9 + 2];
    float R10 = R0[b * 9 + 3], R11 = R0[b * 9 + 4], R12 = R0[b * 9 + 5];
    float R20 = R0[b * 9 + 6], R21 = R0[b * 9 + 7], R22 = R0[b * 9 + 8];

    for (int t = 0; t < T; ++t) {
        f2 cc = *(const f2*)(ct + t * 2);
        float cv = cc.x, cw = cc.y;
        float half_ = (cw * 0.6f) * 0.5f;
        float vLs = cv - half_, vRs = cv + half_;
        float rtn = frsq(R00 * R00 + R10 * R10 + R20 * R20);
        float th0 = R00 * rtn, th1 = R10 * rtn, th2 = R20 * rtn;

        float ic_[2], g0_[2], g1_[2], g2_[2], q0_[2], q1_[2], q2_[2], w_[2];
        float mic_[2], nx_[2], ny_[2], nz_[2], st0_[2], st1_[2], st2_[2];
        float rl0_[2], rl1_[2], rl2_[2];
        float Pz_[2], xp0_[2], xp1_[2], xp2_[2];
        float w00_[2], w10_[2], w01_[2], w11_[2];
        int u0_[2], v0_[2];
        bool interior = true;

        #pragma unroll
        for (int q = 0; q < 2; ++q) {
            float rx = R00 * ppx[q] + R01 * ppy[q] + R02 * ppz[q];
            float ry = R10 * ppx[q] + R11 * ppy[q] + R12 * ppz[q];
            float rz = R20 * ppx[q] + R21 * ppy[q] + R22 * ppz[q];
            float Px = rx + X0, Py = ry + X1, Pz = rz + X2;
            float l0 = Px - X0, l1 = Py - X1, l2 = Pz - X2;
            xp0_[q] = V0 + (W1 * l2 - W2 * l1);
            xp1_[q] = V1 + (W2 * l0 - W0 * l2);
            xp2_[q] = V2 + (W0 * l1 - W1 * l0);
            rl0_[q] = l0; rl1_[q] = l1; rl2_[q] = l2;
            float u = fminf(fmaxf((Px + 12.8f) * 10.0f, 0.0f), 254.999f);
            float vvq = fminf(fmaxf((Py + 12.8f) * 10.0f, 0.0f), 254.999f);
            int u0 = (int)u, v0 = (int)vvq;
            float du = u - (float)u0, dv = vvq - (float)v0;
            w00_[q] = (1.0f - du) * (1.0f - dv);
            w10_[q] = du * (1.0f - dv);
            w01_[q] = (1.0f - du) * dv;
            w11_[q] = du * dv;
            u0_[q] = u0; v0_[q] = v0; Pz_[q] = Pz;
            interior &= (u0 >= 1) & (u0 <= 253) & (v0 >= 1) & (v0 <= 253);
        }

        bool fast = __all(interior);
        #pragma unroll
        for (int q = 0; q < 2; ++q) {
            int u0 = u0_[q], v0 = v0_[q];
            float w00 = w00_[q], w10 = w10_[q], w01 = w01_[q], w11 = w11_[q];
            float zz, fr, gxs, gys;
            if (fast) {
                int base = (u0 - 1) * GW + (v0 - 1);
                f4 P0 = *(const f4*)(zg + base);
                f4 P1 = *(const f4*)(zg + base + GW);
                f4 P2 = *(const f4*)(zg + base + 2 * GW);
                f4 P3 = *(const f4*)(zg + base + 3 * GW);
                int fb = u0 * GW + v0;
                f2 F0 = *(const f2*)(fg + fb);
                f2 F1 = *(const f2*)(fg + fb + GW);
                zz = P1.y * w00 + P2.y * w10 + P1.z * w01 + P2.z * w11;
                fr = F0.x * w00 + F1.x * w10 + F0.y * w01 + F1.y * w11;
                float gx00 = (P2.y - P0.y) * 5.0f;
                float gx10 = (P3.y - P1.y) * 5.0f;
                float gx01 = (P2.z - P0.z) * 5.0f;
                float gx11 = (P3.z - P1.z) * 5.0f;
                float gy00 = (P1.z - P1.x) * 5.0f;
                float gy10 = (P2.z - P2.x) * 5.0f;
                float gy01 = (P1.w - P1.y) * 5.0f;
                float gy11 = (P2.w - P2.y) * 5.0f;
                gxs = gx00 * w00 + gx10 * w10 + gx01 * w01 + gx11 * w11;
                gys = gy00 * w00 + gy10 * w10 + gy01 * w01 + gy11 * w11;
            } else {
                int basei = u0 * GW + v0;
                zz = zg[basei] * w00 + zg[basei + GW] * w10 + zg[basei + 1] * w01 + zg[basei + GW + 1] * w11;
                fr = fg[basei] * w00 + fg[basei + GW] * w10 + fg[basei + 1] * w01 + fg[basei + GW + 1] * w11;
                float gx[2][2], gy[2][2];
                #pragma unroll
                for (int ii = 0; ii < 2; ++ii) {
                    int i = u0 + ii;
                    int ipu = (i < GH - 1) ? i + 1 : i;
                    int imu = (i > 0) ? i - 1 : i;
                    float scu = (ipu - imu == 2) ? 0.5f : 1.0f;
                    #pragma unroll
                    for (int jj = 0; jj < 2; ++jj) {
                        int j = v0 + jj;
                        int jpv = (j < GW - 1) ? j + 1 : j;
                        int jmv = (j > 0) ? j - 1 : j;
                        float scv = (jpv - jmv == 2) ? 0.5f : 1.0f;
                        gx[ii][jj] = ((zg[ipu * GW + j] - zg[imu * GW + j]) * scu) * 10.0f;
                        gy[ii][jj] = ((zg[i * GW + jpv] - zg[i * GW + jmv]) * scv) * 10.0f;
                    }
                }
                gxs = gx[0][0] * w00 + gx[1][0] * w10 + gx[0][1] * w01 + gx[1][1] * w11;
                gys = gy[0][0] * w00 + gy[1][0] * w10 + gy[0][1] * w01 + gy[1][1] * w11;
            }

            float rn = frsq(gxs * gxs + gys * gys + 1.0f);
            float nx = -gxs * rn, ny = -gys * rn, nzc = rn;
            float dh = Pz_[q] - zz;
            float ex = fexp2(dh * 14.426950408889634f);
            float ic = frcp(1.0f + ex);
            float xdn = xp0_[q] * nx + xp1_[q] * ny + xp2_[q] * nzc;

            float mag = -(1000.0f * dh + 100.0f * xdn);
            float mic = mag * ic;
            float m_abs = fabsf(mic);
            float cmd = isL[q] ? vLs : vRs;
            float sl0 = fr * (cmd * th0 - xp0_[q]);
            float sl1 = fr * (cmd * th1 - xp1_[q]);
            float sl2 = fr * (cmd * th2 - xp2_[q]);
            float sdn = sl0 * nx + sl1 * ny + sl2 * nzc;
            float st0 = sl0 - sdn * nx;
            float st1 = sl1 - sdn * ny;
            float st2 = sl2 - sdn * nzc;
            float g0 = mic * nx  + m_abs * st0;
            float g1 = mic * ny  + m_abs * st1;
            float g2 = mic * nzc + m_abs * st2;
            ic_[q] = ic; mic_[q] = mic;
            nx_[q] = nx; ny_[q] = ny; nz_[q] = nzc;
            st0_[q] = st0; st1_[q] = st1; st2_[q] = st2;
            g0_[q] = g0; g1_[q] = g1; g2_[q] = g2;
            q0_[q] = rl1_[q] * g2 - rl2_[q] * g1;
            q1_[q] = rl2_[q] * g0 - rl0_[q] * g2;
            q2_[q] = rl0_[q] * g1 - rl1_[q] * g0;
            float stm = fmaxf(fmaxf(fabsf(st0), fabsf(st1)), fabsf(st2));
            w_[q] = fmaxf(stm, 1.0f) * m_abs;
        }

        float sic = rl63(wave_sum63(ic_[0] + ic_[1]));
        float rg0 = rl63(wave_sum63(g0_[0] + g0_[1]));
        float rg1 = rl63(wave_sum63(g1_[0] + g1_[1]));
        float rg2 = rl63(wave_sum63(g2_[0] + g2_[1]));
        float rq0 = rl63(wave_sum63(q0_[0] + q0_[1]));
        float rq1 = rl63(wave_sum63(q1_[0] + q1_[1]));
        float rq2 = rl63(wave_sum63(q2_[0] + q2_[1]));
        float rw  = rl63(wave_max63(fmaxf(w_[0], w_[1])));
        float rsic = frcp(sic);

        float FT0, FT1, FT2, TQ0, TQ1, TQ2;
        if (rw <= 391.0f * sic) {
            FT0 = rg0 * rsic; FT1 = rg1 * rsic; FT2 = rg2 * rsic;
            TQ0 = rq0 * rsic; TQ1 = rq1 * rsic; TQ2 = rq2 * rsic;
        } else {
            float S0a = 0.f, S1a = 0.f, S2a = 0.f, U0a = 0.f, U1a = 0.f, U2a = 0.f;
            #pragma unroll
            for (int q = 0; q < 2; ++q) {
                float s = mic_[q] * rsic;
                float Fr0 = fminf(fmaxf(s * nx_[q], -392.0f), 392.0f);
                float Fr1 = fminf(fmaxf(s * ny_[q], -392.0f), 392.0f);
                float Fr2 = fminf(fmaxf(s * nz_[q], -392.0f), 392.0f);
                float Nm = __builtin_amdgcn_sqrtf(Fr0 * Fr0 + Fr1 * Fr1 + Fr2 * Fr2);
                float Ff0 = fminf(fmaxf(Nm * st0_[q], -392.0f), 392.0f);
                float Ff1 = fminf(fmaxf(Nm * st1_[q], -392.0f), 392.0f);
                float Ff2 = fminf(fmaxf(Nm * st2_[q], -392.0f), 392.0f);
                float S0 = Fr0 + Ff0, S1 = Fr1 + Ff1, S2 = Fr2 + Ff2;
                S0a += S0; S1a += S1; S2a += S2;
                U0a += rl1_[q] * S2 - rl2_[q] * S1;
                U1a += rl2_[q] * S0 - rl0_[q] * S2;
                U2a += rl0_[q] * S1 - rl1_[q] * S0;
            }
            FT0 = rl63(wave_sum63(S0a));
            FT1 = rl63(wave_sum63(S1a));
            FT2 = rl63(wave_sum63(S2a));
            TQ0 = rl63(wave_sum63(U0a));
            TQ1 = rl63(wave_sum63(U1a));
            TQ2 = rl63(wave_sum63(U2a));
        }

        float od0 = fminf(fmaxf(TQ0 * i00 + TQ1 * i01 + TQ2 * i02, -2.0f), 2.0f);
        float od1 = fminf(fmaxf(TQ0 * i01 + TQ1 * i11 + TQ2 * i12, -2.0f), 2.0f);
        float od2 = fminf(fmaxf(TQ0 * i02 + TQ1 * i12 + TQ2 * i22, -2.0f), 2.0f);

        V0 += (FT0 * 0.025f) * 0.01f;
        V1 += (FT1 * 0.025f) * 0.01f;
        V2 += ((-392.0f + FT2) * 0.025f) * 0.01f;
        X0 += V0 * 0.01f; X1 += V1 * 0.01f; X2 += V2 * 0.01f;
        W0 += od0 * 0.01f; W1 += od1 * 0.01f; W2 += od2 * 0.01f;

        if (lane == 0) {
            ob[t * 3 + 0] = X0;
            ob[t * 3 + 1] = X1;
            ob[t * 3 + 2] = X2;
        }

        float th2s = W0 * W0 + W1 * W1 + W2 * W2;
        float a2 = th2s * 1e-4f;
        float s1 = 0.01f - a2 * (0.01f / 6.0f);
        float c2 = 5e-5f - a2 * (1e-4f / 24.0f);
        float w01p = W0 * W1, w02p = W0 * W2, w12p = W1 * W2;
        float A00 = 1.0f - c2 * (W1 * W1 + W2 * W2);
        float A11 = 1.0f - c2 * (W0 * W0 + W2 * W2);
        float A22 = 1.0f - c2 * (W0 * W0 + W1 * W1);
        float A01 = c2 * w01p - s1 * W2;
        float A10 = c2 * w01p + s1 * W2;
        float A02 = c2 * w02p + s1 * W1;
        float A20 = c2 * w02p - s1 * W1;
        float A12 = c2 * w12p - s1 * W0;
        float A21 = c2 * w12p + s1 * W0;
        float N00 = R00 * A00 + R01 * A10 + R02 * A20;
        float N01 = R00 * A01 + R01 * A11 + R02 * A21;
        float N02 = R00 * A02 + R01 * A12 + R02 * A22;
        float N10 = R10 * A00 + R11 * A10 + R12 * A20;
        float N11 = R10 * A01 + R11 * A11 + R12 * A21;
        float N12 = R10 * A02 + R11 * A12 + R12 * A22;
        float N20 = R20 * A00 + R21 * A10 + R22 * A20;
        float N21 = R20 * A01 + R21 * A11 + R22 * A21;
        float N22 = R20 * A02 + R21 * A12 + R22 * A22;
        R00 = N00; R01 = N01; R02 = N02;
        R10 = N10; R11 = N11; R12 = N12;
        R20 = N20; R21 = N21; R22 = N22;
    }
}

extern "C" void kernel_launch(void* const* d_in, const int* in_sizes, int n_in,
                              void* d_out, int out_size, void* d_ws, size_t ws_size,
                              hipStream_t stream) {
    const float* z_grid       = (const float*)d_in[0];
    const float* friction     = (const float*)d_in[1];
    const float* controls     = (const float*)d_in[2];
    const float* robot_points = (const float*)d_in[3];
    const float* x0           = (const float*)d_in[4];
    const float* xd0          = (const float*)d_in[5];
    const float* R0           = (const float*)d_in[6];
    const float* omega0       = (const float*)d_in[7];
    int B = in_sizes[4] / 3;                 // 64
    int T = in_sizes[2] / (B * 2);           // 500
    size_t need = (size_t)B * GH * GW * sizeof(float) * 4;
    if (ws_size >= need) {
        prep_kernel<<<dim3(GH, B), GW, 0, stream>>>(z_grid, friction, (f4*)d_ws);
        dphys_kernel<<<B, 64, 0, stream>>>((const f4*)d_ws, controls, robot_points,
                                           x0, xd0, R0, omega0, (float*)d_out, T);
    } else {
        dphys_kernel_fb<<<B, 64, 0, stream>>>(z_grid, friction, controls, robot_points,
                                              x0, xd0, R0, omega0, (float*)d_out, T);
    }
}

// Round 15
// 446.698 us; speedup vs baseline: 1.0644x; 1.0644x over previous
//
#include <hip/hip_runtime.h>
#include <math.h>

#define GH 256
#define GW 256

typedef float f4 __attribute__((ext_vector_type(4), aligned(4)));
typedef float f2 __attribute__((ext_vector_type(2), aligned(4)));
typedef float f4l __attribute__((ext_vector_type(4)));   // 16B-aligned

template<int CTRL, int RMASK>
__device__ __forceinline__ float dpp_add(float v) {
    int r = __builtin_amdgcn_update_dpp(0, __builtin_bit_cast(int, v), CTRL, RMASK, 0xF, true);
    return v + __builtin_bit_cast(float, r);
}
template<int CTRL, int RMASK>
__device__ __forceinline__ float dpp_max(float v) {
    int r = __builtin_amdgcn_update_dpp(0, __builtin_bit_cast(int, v), CTRL, RMASK, 0xF, true);
    return fmaxf(v, __builtin_bit_cast(float, r));
}
__device__ __forceinline__ float wave_sum63(float v) {
    v = dpp_add<0xB1, 0xF>(v);
    v = dpp_add<0x4E, 0xF>(v);
    v = dpp_add<0x141, 0xF>(v);
    v = dpp_add<0x140, 0xF>(v);
    v = dpp_add<0x142, 0xA>(v);
    v = dpp_add<0x143, 0xC>(v);
    return v;
}
__device__ __forceinline__ float wave_max63(float v) {
    v = dpp_max<0xB1, 0xF>(v);
    v = dpp_max<0x4E, 0xF>(v);
    v = dpp_max<0x141, 0xF>(v);
    v = dpp_max<0x140, 0xF>(v);
    v = dpp_max<0x142, 0xA>(v);
    v = dpp_max<0x143, 0xC>(v);
    return v;
}
__device__ __forceinline__ float rl63(float v) {
    return __builtin_bit_cast(float, __builtin_amdgcn_readlane(__builtin_bit_cast(int, v), 63));
}
__device__ __forceinline__ float frcp(float x)  { return __builtin_amdgcn_rcpf(x); }
__device__ __forceinline__ float frsq(float x)  { return __builtin_amdgcn_rsqf(x); }
__device__ __forceinline__ float fexp2(float x) { return __builtin_amdgcn_exp2f(x); }

// LDS-only barrier: drain LDS ops, sync waves (avoids __syncthreads' vmcnt(0) drain).
#define LDS_BARRIER() asm volatile("s_waitcnt lgkmcnt(0)\n\ts_barrier" ::: "memory")

// ---------- prep: per-cell {z, gx, gy, fr} with exact edge semantics ----------
__global__ __launch_bounds__(256) void prep_kernel(
    const float* __restrict__ z_grid,
    const float* __restrict__ friction,
    f4* __restrict__ tex)
{
    const int j = threadIdx.x;
    const int i = blockIdx.x;
    const int b = blockIdx.y;
    const float* __restrict__ z = z_grid + (size_t)b * (GH * GW);
    int ipu = (i < GH - 1) ? i + 1 : i;
    int imu = (i > 0) ? i - 1 : i;
    int jpv = (j < GW - 1) ? j + 1 : j;
    int jmv = (j > 0) ? j - 1 : j;
    float scu = (ipu - imu == 2) ? 0.5f : 1.0f;
    float scv = (jpv - jmv == 2) ? 0.5f : 1.0f;
    float gx = ((z[ipu * GW + j] - z[imu * GW + j]) * scu) * 10.0f;
    float gy = ((z[i * GW + jpv] - z[i * GW + jmv]) * scv) * 10.0f;
    f4 o;
    o.x = z[i * GW + j];
    o.y = gx;
    o.z = gy;
    o.w = friction[(size_t)b * (GH * GW) + i * GW + j];
    tex[(size_t)b * (GH * GW) + i * GW + j] = o;
}

// Prefetch phase for step TN: build A from (updated) W, compute next pts via
// R_t·(A·p) [associativity: (R·A)·p == R·(A·p) up to 1ulp], issue tex loads,
// THEN complete the full R = R·A update under the load latency.
#define PREFETCH(TN)                                                            \
do {                                                                            \
    cc = *(const f2*)(ct + (TN) * 2);                                           \
    float th2s = W0 * W0 + W1 * W1 + W2 * W2;                                   \
    float a2 = th2s * 1e-4f;                                                    \
    float s1 = 0.01f - a2 * (0.01f / 6.0f);                                     \
    float c2 = 5e-5f - a2 * (1e-4f / 24.0f);                                    \
    float w01p = W0 * W1, w02p = W0 * W2, w12p = W1 * W2;                       \
    float A00 = 1.0f - c2 * (W1 * W1 + W2 * W2);                                \
    float A11 = 1.0f - c2 * (W0 * W0 + W2 * W2);                                \
    float A22 = 1.0f - c2 * (W0 * W0 + W1 * W1);                                \
    float A01 = c2 * w01p - s1 * W2;                                            \
    float A10 = c2 * w01p + s1 * W2;                                            \
    float A02 = c2 * w02p + s1 * W1;                                            \
    float A20 = c2 * w02p - s1 * W1;                                            \
    float A12 = c2 * w12p - s1 * W0;                                            \
    float A21 = c2 * w12p + s1 * W0;                                            \
    float ap0 = A00 * ppx + A01 * ppy + A02 * ppz;                              \
    float ap1 = A10 * ppx + A11 * ppy + A12 * ppz;                              \
    float ap2 = A20 * ppx + A21 * ppy + A22 * ppz;                              \
    float rp0 = R00 * ap0 + R01 * ap1 + R02 * ap2;                              \
    float rp1 = R10 * ap0 + R11 * ap1 + R12 * ap2;                              \
    float rp2 = R20 * ap0 + R21 * ap1 + R22 * ap2;                              \
    Px = rp0 + X0; Py = rp1 + X1; Pz = rp2 + X2;                                \
    l0 = Px - X0; l1 = Py - X1; l2 = Pz - X2;                                   \
    float u_ = fminf(fmaxf((Px + 12.8f) * 10.0f, 0.0f), 254.999f);              \
    float v_ = fminf(fmaxf((Py + 12.8f) * 10.0f, 0.0f), 254.999f);              \
    int u0_ = (int)u_, v0_ = (int)v_;                                           \
    du = u_ - (float)u0_; dv = v_ - (float)v0_;                                 \
    int idx_ = (u0_ << 8) + v0_;                                                \
    c00 = tb[idx_];                                                             \
    c01 = tb[idx_ + 1];                                                         \
    c10 = tb[idx_ + GW];                                                        \
    c11 = tb[idx_ + GW + 1];                                                    \
    /* full R update (27 fma) hides under the loads just issued */              \
    float N00 = R00 * A00 + R01 * A10 + R02 * A20;                              \
    float N01 = R00 * A01 + R01 * A11 + R02 * A21;                              \
    float N02 = R00 * A02 + R01 * A12 + R02 * A22;                              \
    float N10 = R10 * A00 + R11 * A10 + R12 * A20;                              \
    float N11 = R10 * A01 + R11 * A11 + R12 * A21;                              \
    float N12 = R10 * A02 + R11 * A12 + R12 * A22;                              \
    float N20 = R20 * A00 + R21 * A10 + R22 * A20;                              \
    float N21 = R20 * A01 + R21 * A11 + R22 * A21;                              \
    float N22 = R20 * A02 + R21 * A12 + R22 * A22;                              \
    R00 = N00; R01 = N01; R02 = N02;                                            \
    R10 = N10; R11 = N11; R12 = N12;                                            \
    R20 = N20; R21 = N21; R22 = N22;                                            \
} while (0)

// One simulated step (rotated schedule: loads for TCUR already in flight).
#define STEP_BODY(TCUR, PH)                                                     \
do {                                                                            \
    const int par_ = (PH < 0) ? ((TCUR) & 1) : ((PH) & 1);                      \
    /* load-shadow work (uses state at TCUR; R already = R_TCUR) */             \
    float cv = cc.x, cw = cc.y;                                                 \
    float half_ = (cw * 0.6f) * 0.5f;                                           \
    float vLs = cv - half_, vRs = cv + half_;                                   \
    float xp0 = V0 + (W1 * l2 - W2 * l1);                                       \
    float xp1 = V1 + (W2 * l0 - W0 * l2);                                       \
    float xp2 = V2 + (W0 * l1 - W1 * l0);                                       \
    float cmd = isL ? vLs : vRs;                                                \
    float ct0 = cmd * R00 - xp0;                                                \
    float ct1 = cmd * R10 - xp1;                                                \
    float ct2 = cmd * R20 - xp2;                                                \
    float w00 = (1.0f - du) * (1.0f - dv);                                      \
    float w10 = du * (1.0f - dv);                                               \
    float w01 = (1.0f - du) * dv;                                               \
    float w11 = du * dv;                                                        \
    /* bilinear blend of {z, gx, gy, fr} */                                     \
    f4 cb = c00 * w00 + c10 * w10 + c01 * w01 + c11 * w11;                      \
    float zz = cb.x, gxs = cb.y, gys = cb.z, fr = cb.w;                         \
    float rn = frsq(gxs * gxs + gys * gys + 1.0f);                              \
    float nx = -gxs * rn, ny = -gys * rn, nzc = rn;                             \
    float dh = Pz - zz;                                                         \
    float ex = fexp2(dh * 14.426950408889634f);                                 \
    float ic = frcp(1.0f + ex);                                                 \
    float xdn = xp0 * nx + xp1 * ny + xp2 * nzc;                                \
    float mag = -(1000.0f * dh + 100.0f * xdn);                                 \
    float mic = mag * ic;                                                       \
    float m_abs = fabsf(mic);                                                   \
    float sl0 = fr * ct0, sl1 = fr * ct1, sl2 = fr * ct2;                       \
    float sdn = sl0 * nx + sl1 * ny + sl2 * nzc;                                \
    float st0 = sl0 - sdn * nx;                                                 \
    float st1 = sl1 - sdn * ny;                                                 \
    float st2 = sl2 - sdn * nzc;                                                \
    float g0 = mic * nx  + m_abs * st0;                                         \
    float g1 = mic * ny  + m_abs * st1;                                         \
    float g2 = mic * nzc + m_abs * st2;                                         \
    float q0 = l1 * g2 - l2 * g1;                                               \
    float q1 = l2 * g0 - l0 * g2;                                               \
    float q2 = l0 * g1 - l1 * g0;                                               \
    float stm = fmaxf(fmaxf(fabsf(st0), fabsf(st1)), fabsf(st2));               \
    float worst = fmaxf(stm, 1.0f) * m_abs;                                     \
    /* 8 pipelined DPP chains; own via readlane, other via LDS */               \
    float d_ic = wave_sum63(ic);                                                \
    float d_g0 = wave_sum63(g0), d_g1 = wave_sum63(g1), d_g2 = wave_sum63(g2);  \
    float d_q0 = wave_sum63(q0), d_q1 = wave_sum63(q1), d_q2 = wave_sum63(q2);  \
    float d_rw = wave_max63(worst);                                             \
    if ((tid & 63) == 63) {                                                     \
        f4l h0; h0.x = d_g0; h0.y = d_g1; h0.z = d_g2; h0.w = d_q0;             \
        f4l h1; h1.x = d_q1; h1.y = d_q2; h1.z = d_ic; h1.w = d_rw;             \
        ldsX[par_][wv][0] = h0; ldsX[par_][wv][1] = h1;                         \
    }                                                                           \
    float o_ic = rl63(d_ic);                                                    \
    float o_g0 = rl63(d_g0), o_g1 = rl63(d_g1), o_g2 = rl63(d_g2);              \
    float o_q0 = rl63(d_q0), o_q1 = rl63(d_q1), o_q2 = rl63(d_q2);              \
    float o_rw = rl63(d_rw);                                                    \
    LDS_BARRIER();                                                              \
    f4l e0 = ldsX[par_][wv ^ 1][0], e1 = ldsX[par_][wv ^ 1][1];                 \
    float sic = o_ic + e1.z;                                                    \
    float rwm = fmaxf(o_rw, e1.w);                                              \
    float rsic = frcp(sic);                                                     \
    float FT0, FT1, FT2, TQ0, TQ1, TQ2;                                         \
    if (rwm <= 391.0f * sic) {                                                  \
        FT0 = (o_g0 + e0.x) * rsic;                                             \
        FT1 = (o_g1 + e0.y) * rsic;                                             \
        FT2 = (o_g2 + e0.z) * rsic;                                             \
        TQ0 = (o_q0 + e0.w) * rsic;                                             \
        TQ1 = (o_q1 + e1.x) * rsic;                                             \
        TQ2 = (o_q2 + e1.y) * rsic;                                             \
    } else {                                                                    \
        float s = mic * rsic;                                                   \
        float Fr0 = fminf(fmaxf(s * nx,  -392.0f), 392.0f);                     \
        float Fr1 = fminf(fmaxf(s * ny,  -392.0f), 392.0f);                     \
        float Fr2 = fminf(fmaxf(s * nzc, -392.0f), 392.0f);                     \
        float Nm = __builtin_amdgcn_sqrtf(Fr0 * Fr0 + Fr1 * Fr1 + Fr2 * Fr2);   \
        float Ff0 = fminf(fmaxf(Nm * st0, -392.0f), 392.0f);                    \
        float Ff1 = fminf(fmaxf(Nm * st1, -392.0f), 392.0f);                    \
        float Ff2 = fminf(fmaxf(Nm * st2, -392.0f), 392.0f);                    \
        float S0 = Fr0 + Ff0, S1 = Fr1 + Ff1, S2 = Fr2 + Ff2;                   \
        float U0 = l1 * S2 - l2 * S1;                                           \
        float U1 = l2 * S0 - l0 * S2;                                           \
        float U2 = l0 * S1 - l1 * S0;                                           \
        float dS0 = wave_sum63(S0), dS1 = wave_sum63(S1), dS2 = wave_sum63(S2); \
        float dU0 = wave_sum63(U0), dU1 = wave_sum63(U1), dU2 = wave_sum63(U2); \
        if ((tid & 63) == 63) {                                                 \
            f4l h0; h0.x = dS0; h0.y = dS1; h0.z = dS2; h0.w = dU0;             \
            f4l h1; h1.x = dU1; h1.y = dU2; h1.z = 0.f; h1.w = 0.f;             \
            ldsY[wv][0] = h0; ldsY[wv][1] = h1;                                 \
        }                                                                       \
        LDS_BARRIER();                                                          \
        f4l c0 = ldsY[wv ^ 1][0], c1 = ldsY[wv ^ 1][1];                         \
        FT0 = rl63(dS0) + c0.x; FT1 = rl63(dS1) + c0.y; FT2 = rl63(dS2) + c0.z; \
        TQ0 = rl63(dU0) + c0.w; TQ1 = rl63(dU1) + c1.x; TQ2 = rl63(dU2) + c1.y; \
    }                                                                           \
    float od0 = fminf(fmaxf(TQ0 * i00 + TQ1 * i01 + TQ2 * i02, -2.0f), 2.0f);   \
    float od1 = fminf(fmaxf(TQ0 * i01 + TQ1 * i11 + TQ2 * i12, -2.0f), 2.0f);   \
    float od2 = fminf(fmaxf(TQ0 * i02 + TQ1 * i12 + TQ2 * i22, -2.0f), 2.0f);   \
    V0 += (FT0 * 0.025f) * 0.01f;                                               \
    V1 += (FT1 * 0.025f) * 0.01f;                                               \
    V2 += ((-392.0f + FT2) * 0.025f) * 0.01f;                                   \
    X0 += V0 * 0.01f; X1 += V1 * 0.01f; X2 += V2 * 0.01f;                       \
    W0 += od0 * 0.01f; W1 += od1 * 0.01f; W2 += od2 * 0.01f;                    \
    /* prefetch next step (issues tex loads; R update hides under them) */      \
    {                                                                           \
        int tn_ = ((TCUR) + 1 < T) ? (TCUR) + 1 : T - 1;                        \
        PREFETCH(tn_);                                                          \
    }                                                                           \
    if (PH < 0) {                                                               \
        if (tid == 0) {                                                         \
            ob[(TCUR) * 3 + 0] = X0;                                            \
            ob[(TCUR) * 3 + 1] = X1;                                            \
            ob[(TCUR) * 3 + 2] = X2;                                            \
        }                                                                       \
    } else if (PH == 0) { sb0.x = X0; sb0.y = X1; sb0.z = X2; }                 \
    else if (PH == 1) { sb0.w = X0; sb1.x = X1; sb1.y = X2; }                   \
    else if (PH == 2) { sb1.z = X0; sb1.w = X1; sb2.x = X2; }                   \
    else {                                                                      \
        sb2.y = X0; sb2.z = X1; sb2.w = X2;                                     \
        if (tid == 0) {                                                         \
            f4* op = (f4*)(ob + ((TCUR) - 3) * 3);                              \
            op[0] = sb0; op[1] = sb1; op[2] = sb2;                              \
        }                                                                       \
    }                                                                           \
} while (0)

// ---------- main sim kernel (texture path) ----------
__global__ __launch_bounds__(128) void dphys_kernel(
    const f4* __restrict__ tex,
    const float* __restrict__ controls,
    const float* __restrict__ robot_points,
    const float* __restrict__ x0,
    const float* __restrict__ xd0,
    const float* __restrict__ R0,
    const float* __restrict__ omega0,
    float* __restrict__ out,
    int T)
{
    const int b = blockIdx.x;
    const int tid = threadIdx.x;
    const int wv = tid >> 6;
    __shared__ f4l ldsX[2][2][2];
    __shared__ f4l ldsY[2][2];

    const f4* __restrict__ tb = tex + (size_t)b * (GH * GW);
    const float* __restrict__ ct = controls + (size_t)b * (T * 2);
    float* __restrict__ ob = out + (size_t)b * (T * 3);

    const float ppx = robot_points[tid * 3 + 0];
    const float ppy = robot_points[tid * 3 + 1];
    const float ppz = robot_points[tid * 3 + 2];
    const bool isL = (ppy < 0.0f);

    // inertia (one-time)
    float I6[6];
    I6[0] = ppy * ppy + ppz * ppz;
    I6[1] = ppx * ppx + ppz * ppz;
    I6[2] = ppx * ppx + ppy * ppy;
    I6[3] = ppx * ppy;
    I6[4] = ppx * ppz;
    I6[5] = ppy * ppz;
    #pragma unroll
    for (int k = 0; k < 6; ++k) I6[k] = rl63(wave_sum63(I6[k]));
    if ((tid & 63) == 63) {
        f4l t0; t0.x = I6[0]; t0.y = I6[1]; t0.z = I6[2]; t0.w = I6[3];
        f4l t1; t1.x = I6[4]; t1.y = I6[5]; t1.z = 0.f; t1.w = 0.f;
        ldsY[wv][0] = t0; ldsY[wv][1] = t1;
    }
    __syncthreads();
    {
        f4l o0 = ldsY[wv ^ 1][0], o1 = ldsY[wv ^ 1][1];
        I6[0] += o0.x; I6[1] += o0.y; I6[2] += o0.z;
        I6[3] += o0.w; I6[4] += o1.x; I6[5] += o1.y;
    }
    const float mp = 0.3125f;
    {
        double a = mp * I6[0], bb = mp * I6[1], c = mp * I6[2];
        double d = -(mp * I6[3]), e = -(mp * I6[4]), f = -(mp * I6[5]);
        double C00 = bb * c - f * f, C01 = e * f - d * c, C02 = d * f - bb * e;
        double C11 = a * c - e * e, C12 = d * e - a * f, C22 = a * bb - d * d;
        double idet = 1.0 / (a * C00 + d * C01 + e * C02);
        I6[0] = (float)(C00 * idet); I6[1] = (float)(C11 * idet); I6[2] = (float)(C22 * idet);
        I6[3] = (float)(C01 * idet); I6[4] = (float)(C02 * idet); I6[5] = (float)(C12 * idet);
    }
    const float i00 = I6[0], i11 = I6[1], i22 = I6[2];
    const float i01 = I6[3], i02 = I6[4], i12 = I6[5];

    float X0 = x0[b * 3 + 0], X1 = x0[b * 3 + 1], X2 = x0[b * 3 + 2];
    float V0 = xd0[b * 3 + 0], V1 = xd0[b * 3 + 1], V2 = xd0[b * 3 + 2];
    float W0 = omega0[b * 3 + 0], W1 = omega0[b * 3 + 1], W2 = omega0[b * 3 + 2];
    float R00 = R0[b * 9 + 0], R01 = R0[b * 9 + 1], R02 = R0[b * 9 + 2];
    float R10 = R0[b * 9 + 3], R11 = R0[b * 9 + 4], R12 = R0[b * 9 + 5];
    float R20 = R0[b * 9 + 6], R21 = R0[b * 9 + 7], R22 = R0[b * 9 + 8];

    f4 sb0, sb1, sb2;                 // 4-step output buffer
    f2 cc;                            // controls for current step
    float Px, Py, Pz, l0, l1, l2, du, dv;   // pipelined position/address state
    f4 c00, c01, c10, c11;            // pipelined texture loads

    // prologue: step-0 addresses + loads from R0, X0 directly
    cc = *(const f2*)(ct);
    {
        float rx = R00 * ppx + R01 * ppy + R02 * ppz;
        float ry = R10 * ppx + R11 * ppy + R12 * ppz;
        float rz = R20 * ppx + R21 * ppy + R22 * ppz;
        Px = rx + X0; Py = ry + X1; Pz = rz + X2;
        l0 = Px - X0; l1 = Py - X1; l2 = Pz - X2;
        float u_ = fminf(fmaxf((Px + 12.8f) * 10.0f, 0.0f), 254.999f);
        float v_ = fminf(fmaxf((Py + 12.8f) * 10.0f, 0.0f), 254.999f);
        int u0_ = (int)u_, v0_ = (int)v_;
        du = u_ - (float)u0_; dv = v_ - (float)v0_;
        int idx_ = (u0_ << 8) + v0_;
        c00 = tb[idx_]; c01 = tb[idx_ + 1]; c10 = tb[idx_ + GW]; c11 = tb[idx_ + GW + 1];
    }

    int t = 0;
    for (; t + 3 < T; t += 4) {
        STEP_BODY(t + 0, 0);
        STEP_BODY(t + 1, 1);
        STEP_BODY(t + 2, 2);
        STEP_BODY(t + 3, 3);
    }
    for (; t < T; ++t) {
        STEP_BODY(t, -1);
    }
}

// ---------- fallback (no-workspace path; R7/R8 structure) ----------
__global__ __launch_bounds__(128) void dphys_kernel_fb(
    const float* __restrict__ z_grid,
    const float* __restrict__ friction,
    const float* __restrict__ controls,
    const float* __restrict__ robot_points,
    const float* __restrict__ x0,
    const float* __restrict__ xd0,
    const float* __restrict__ R0,
    const float* __restrict__ omega0,
    float* __restrict__ out,
    int T)
{
    const int b = blockIdx.x;
    const int tid = threadIdx.x;
    const int wv = tid >> 6;
    __shared__ f4l ldsX[2][2][2];
    __shared__ f4l ldsY[2][2];

    const float* __restrict__ zg = z_grid + (size_t)b * (GH * GW);
    const float* __restrict__ fg = friction + (size_t)b * (GH * GW);
    const float* __restrict__ ct = controls + (size_t)b * (T * 2);
    float* __restrict__ ob = out + (size_t)b * (T * 3);

    const float ppx = robot_points[tid * 3 + 0];
    const float ppy = robot_points[tid * 3 + 1];
    const float ppz = robot_points[tid * 3 + 2];
    const bool isL = (ppy < 0.0f);

    float I6[6];
    I6[0] = ppy * ppy + ppz * ppz;
    I6[1] = ppx * ppx + ppz * ppz;
    I6[2] = ppx * ppx + ppy * ppy;
    I6[3] = ppx * ppy;
    I6[4] = ppx * ppz;
    I6[5] = ppy * ppz;
    #pragma unroll
    for (int k = 0; k < 6; ++k) I6[k] = rl63(wave_sum63(I6[k]));
    if ((tid & 63) == 63) {
        f4l t0; t0.x = I6[0]; t0.y = I6[1]; t0.z = I6[2]; t0.w = I6[3];
        f4l t1; t1.x = I6[4]; t1.y = I6[5]; t1.z = 0.f; t1.w = 0.f;
        ldsY[wv][0] = t0; ldsY[wv][1] = t1;
    }
    __syncthreads();
    {
        f4l o0 = ldsY[wv ^ 1][0], o1 = ldsY[wv ^ 1][1];
        I6[0] += o0.x; I6[1] += o0.y; I6[2] += o0.z;
        I6[3] += o0.w; I6[4] += o1.x; I6[5] += o1.y;
    }
    const float mp = 0.3125f;
    {
        double a = mp * I6[0], bb = mp * I6[1], c = mp * I6[2];
        double d = -(mp * I6[3]), e = -(mp * I6[4]), f = -(mp * I6[5]);
        double C00 = bb * c - f * f, C01 = e * f - d * c, C02 = d * f - bb * e;
        double C11 = a * c - e * e, C12 = d * e - a * f, C22 = a * bb - d * d;
        double idet = 1.0 / (a * C00 + d * C01 + e * C02);
        I6[0] = (float)(C00 * idet); I6[1] = (float)(C11 * idet); I6[2] = (float)(C22 * idet);
        I6[3] = (float)(C01 * idet); I6[4] = (float)(C02 * idet); I6[5] = (float)(C12 * idet);
    }
    const float i00 = I6[0], i11 = I6[1], i22 = I6[2];
    const float i01 = I6[3], i02 = I6[4], i12 = I6[5];

    float X0 = x0[b * 3 + 0], X1 = x0[b * 3 + 1], X2 = x0[b * 3 + 2];
    float V0 = xd0[b * 3 + 0], V1 = xd0[b * 3 + 1], V2 = xd0[b * 3 + 2];
    float W0 = omega0[b * 3 + 0], W1 = omega0[b * 3 + 1], W2 = omega0[b * 3 + 2];
    float R00 = R0[b * 9 + 0], R01 = R0[b * 9 + 1], R02 = R0[b * 9 + 2];
    float R10 = R0[b * 9 + 3], R11 = R0[b * 9 + 4], R12 = R0[b * 9 + 5];
    float R20 = R0[b * 9 + 6], R21 = R0[b * 9 + 7], R22 = R0[b * 9 + 8];

    for (int t = 0; t < T; ++t) {
        const int par = t & 1;
        f2 cc = *(const f2*)(ct + t * 2);
        float rx = R00 * ppx + R01 * ppy + R02 * ppz;
        float ry = R10 * ppx + R11 * ppy + R12 * ppz;
        float rz = R20 * ppx + R21 * ppy + R22 * ppz;
        float Px = rx + X0, Py = ry + X1, Pz = rz + X2;
        float l0 = Px - X0, l1 = Py - X1, l2 = Pz - X2;
        float u = fminf(fmaxf((Px + 12.8f) * 10.0f, 0.0f), 254.999f);
        float vvq = fminf(fmaxf((Py + 12.8f) * 10.0f, 0.0f), 254.999f);
        int u0 = (int)u, v0 = (int)vvq;
        bool interior = (u0 >= 1) & (u0 <= 253) & (v0 >= 1) & (v0 <= 253);
        bool fastp = __all(interior);

        float zz, fr, gxs, gys;
        float du = u - (float)u0, dv = vvq - (float)v0;
        float w00 = (1.0f - du) * (1.0f - dv);
        float w10 = du * (1.0f - dv);
        float w01 = (1.0f - du) * dv;
        float w11 = du * dv;

        float cv = cc.x, cw = cc.y;
        float half = (cw * 0.6f) * 0.5f;
        float vLs = cv - half, vRs = cv + half;
        float rtn = frsq(R00 * R00 + R10 * R10 + R20 * R20);
        float th0 = R00 * rtn, th1 = R10 * rtn, th2 = R20 * rtn;
        float xp0 = V0 + (W1 * l2 - W2 * l1);
        float xp1 = V1 + (W2 * l0 - W0 * l2);
        float xp2 = V2 + (W0 * l1 - W1 * l0);
        float cmd = isL ? vLs : vRs;
        float ct0 = cmd * th0 - xp0;
        float ct1 = cmd * th1 - xp1;
        float ct2 = cmd * th2 - xp2;

        if (fastp) {
            int base = (u0 - 1) * GW + (v0 - 1);
            f4 P0 = *(const f4*)(zg + base);
            f4 P1 = *(const f4*)(zg + base + GW);
            f4 P2 = *(const f4*)(zg + base + 2 * GW);
            f4 P3 = *(const f4*)(zg + base + 3 * GW);
            int fb = u0 * GW + v0;
            f2 F0 = *(const f2*)(fg + fb);
            f2 F1 = *(const f2*)(fg + fb + GW);
            zz = P1.y * w00 + P2.y * w10 + P1.z * w01 + P2.z * w11;
            fr = F0.x * w00 + F1.x * w10 + F0.y * w01 + F1.y * w11;
            float gx00 = (P2.y - P0.y) * 5.0f;
            float gx10 = (P3.y - P1.y) * 5.0f;
            float gx01 = (P2.z - P0.z) * 5.0f;
            float gx11 = (P3.z - P1.z) * 5.0f;
            float gy00 = (P1.z - P1.x) * 5.0f;
            float gy10 = (P2.z - P2.x) * 5.0f;
            float gy01 = (P1.w - P1.y) * 5.0f;
            float gy11 = (P2.w - P2.y) * 5.0f;
            gxs = gx00 * w00 + gx10 * w10 + gx01 * w01 + gx11 * w11;
            gys = gy00 * w00 + gy10 * w10 + gy01 * w01 + gy11 * w11;
        } else {
            int basei = u0 * GW + v0;
            zz = zg[basei] * w00 + zg[basei + GW] * w10 + zg[basei + 1] * w01 + zg[basei + GW + 1] * w11;
            fr = fg[basei] * w00 + fg[basei + GW] * w10 + fg[basei + 1] * w01 + fg[basei + GW + 1] * w11;
            float gx[2][2], gy[2][2];
            #pragma unroll
            for (int ii = 0; ii < 2; ++ii) {
                int i = u0 + ii;
                int ipu = (i < GH - 1) ? i + 1 : i;
                int imu = (i > 0) ? i - 1 : i;
                float scu = (ipu - imu == 2) ? 0.5f : 1.0f;
                #pragma unroll
                for (int jj = 0; jj < 2; ++jj) {
                    int j = v0 + jj;
                    int jpv = (j < GW - 1) ? j + 1 : j;
                    int jmv = (j > 0) ? j - 1 : j;
                    float scv = (jpv - jmv == 2) ? 0.5f : 1.0f;
                    gx[ii][jj] = ((zg[ipu * GW + j] - zg[imu * GW + j]) * scu) * 10.0f;
                    gy[ii][jj] = ((zg[i * GW + jpv] - zg[i * GW + jmv]) * scv) * 10.0f;
                }
            }
            gxs = gx[0][0] * w00 + gx[1][0] * w10 + gx[0][1] * w01 + gx[1][1] * w11;
            gys = gy[0][0] * w00 + gy[1][0] * w10 + gy[0][1] * w01 + gy[1][1] * w11;
        }

        float rn = frsq(gxs * gxs + gys * gys + 1.0f);
        float nx = -gxs * rn, ny = -gys * rn, nzc = rn;
        float dh = Pz - zz;
        float ex = fexp2(dh * 14.426950408889634f);
        float ic = frcp(1.0f + ex);
        float xdn = xp0 * nx + xp1 * ny + xp2 * nzc;

        float mag = -(1000.0f * dh + 100.0f * xdn);
        float mic = mag * ic;
        float m_abs = fabsf(mic);
        float sl0 = fr * ct0, sl1 = fr * ct1, sl2 = fr * ct2;
        float sdn = sl0 * nx + sl1 * ny + sl2 * nzc;
        float st0 = sl0 - sdn * nx;
        float st1 = sl1 - sdn * ny;
        float st2 = sl2 - sdn * nzc;
        float g0 = mic * nx  + m_abs * st0;
        float g1 = mic * ny  + m_abs * st1;
        float g2 = mic * nzc + m_abs * st2;
        float q0 = l1 * g2 - l2 * g1;
        float q1 = l2 * g0 - l0 * g2;
        float q2 = l0 * g1 - l1 * g0;
        float stm = fmaxf(fmaxf(fabsf(st0), fabsf(st1)), fabsf(st2));
        float worst = fmaxf(stm, 1.0f) * m_abs;

        float d_ic = wave_sum63(ic);
        float d_g0 = wave_sum63(g0), d_g1 = wave_sum63(g1), d_g2 = wave_sum63(g2);
        float d_q0 = wave_sum63(q0), d_q1 = wave_sum63(q1), d_q2 = wave_sum63(q2);
        float d_rw = wave_max63(worst);
        if ((tid & 63) == 63) {
            f4l h0; h0.x = d_g0; h0.y = d_g1; h0.z = d_g2; h0.w = d_q0;
            f4l h1; h1.x = d_q1; h1.y = d_q2; h1.z = d_ic; h1.w = d_rw;
            ldsX[par][wv][0] = h0; ldsX[par][wv][1] = h1;
        }
        float o_ic = rl63(d_ic);
        float o_g0 = rl63(d_g0), o_g1 = rl63(d_g1), o_g2 = rl63(d_g2);
        float o_q0 = rl63(d_q0), o_q1 = rl63(d_q1), o_q2 = rl63(d_q2);
        float o_rw = rl63(d_rw);
        __syncthreads();
        f4l e0 = ldsX[par][wv ^ 1][0], e1 = ldsX[par][wv ^ 1][1];
        float sic = o_ic + e1.z;
        float rwm = fmaxf(o_rw, e1.w);
        float rsic = frcp(sic);

        float FT0, FT1, FT2, TQ0, TQ1, TQ2;
        if (rwm <= 391.0f * sic) {
            FT0 = (o_g0 + e0.x) * rsic;
            FT1 = (o_g1 + e0.y) * rsic;
            FT2 = (o_g2 + e0.z) * rsic;
            TQ0 = (o_q0 + e0.w) * rsic;
            TQ1 = (o_q1 + e1.x) * rsic;
            TQ2 = (o_q2 + e1.y) * rsic;
        } else {
            float s = mic * rsic;
            float Fr0 = fminf(fmaxf(s * nx,  -392.0f), 392.0f);
            float Fr1 = fminf(fmaxf(s * ny,  -392.0f), 392.0f);
            float Fr2 = fminf(fmaxf(s * nzc, -392.0f), 392.0f);
            float Nm = __builtin_amdgcn_sqrtf(Fr0 * Fr0 + Fr1 * Fr1 + Fr2 * Fr2);
            float Ff0 = fminf(fmaxf(Nm * st0, -392.0f), 392.0f);
            float Ff1 = fminf(fmaxf(Nm * st1, -392.0f), 392.0f);
            float Ff2 = fminf(fmaxf(Nm * st2, -392.0f), 392.0f);
            float S0 = Fr0 + Ff0, S1 = Fr1 + Ff1, S2 = Fr2 + Ff2;
            float U0 = l1 * S2 - l2 * S1;
            float U1 = l2 * S0 - l0 * S2;
            float U2 = l0 * S1 - l1 * S0;
            float dS0 = wave_sum63(S0), dS1 = wave_sum63(S1), dS2 = wave_sum63(S2);
            float dU0 = wave_sum63(U0), dU1 = wave_sum63(U1), dU2 = wave_sum63(U2);
            if ((tid & 63) == 63) {
                f4l h0; h0.x = dS0; h0.y = dS1; h0.z = dS2; h0.w = dU0;
                f4l h1; h1.x = dU1; h1.y = dU2; h1.z = 0.f; h1.w = 0.f;
                ldsY[wv][0] = h0; ldsY[wv][1] = h1;
            }
            __syncthreads();
            f4l c0 = ldsY[wv ^ 1][0], c1 = ldsY[wv ^ 1][1];
            FT0 = rl63(dS0) + c0.x; FT1 = rl63(dS1) + c0.y; FT2 = rl63(dS2) + c0.z;
            TQ0 = rl63(dU0) + c0.w; TQ1 = rl63(dU1) + c1.x; TQ2 = rl63(dU2) + c1.y;
        }

        float od0 = fminf(fmaxf(TQ0 * i00 + TQ1 * i01 + TQ2 * i02, -2.0f), 2.0f);
        float od1 = fminf(fmaxf(TQ0 * i01 + TQ1 * i11 + TQ2 * i12, -2.0f), 2.0f);
        float od2 = fminf(fmaxf(TQ0 * i02 + TQ1 * i12 + TQ2 * i22, -2.0f), 2.0f);

        V0 += (FT0 * 0.025f) * 0.01f;
        V1 += (FT1 * 0.025f) * 0.01f;
        V2 += ((-392.0f + FT2) * 0.025f) * 0.01f;
        X0 += V0 * 0.01f; X1 += V1 * 0.01f; X2 += V2 * 0.01f;
        W0 += od0 * 0.01f; W1 += od1 * 0.01f; W2 += od2 * 0.01f;

        if (tid == 0) {
            ob[t * 3 + 0] = X0;
            ob[t * 3 + 1] = X1;
            ob[t * 3 + 2] = X2;
        }

        float th2s = W0 * W0 + W1 * W1 + W2 * W2;
        float a2 = th2s * 1e-4f;
        float s1 = 0.01f - a2 * (0.01f / 6.0f);
        float c2 = 5e-5f - a2 * (1e-4f / 24.0f);
        float w01p = W0 * W1, w02p = W0 * W2, w12p = W1 * W2;
        float A00 = 1.0f - c2 * (W1 * W1 + W2 * W2);
        float A11 = 1.0f - c2 * (W0 * W0 + W2 * W2);
        float A22 = 1.0f - c2 * (W0 * W0 + W1 * W1);
        float A01 = c2 * w01p - s1 * W2;
        float A10 = c2 * w01p + s1 * W2;
        float A02 = c2 * w02p + s1 * W1;
        float A20 = c2 * w02p - s1 * W1;
        float A12 = c2 * w12p - s1 * W0;
        float A21 = c2 * w12p + s1 * W0;
        float N00 = R00 * A00 + R01 * A10 + R02 * A20;
        float N01 = R00 * A01 + R01 * A11 + R02 * A21;
        float N02 = R00 * A02 + R01 * A12 + R02 * A22;
        float N10 = R10 * A00 + R11 * A10 + R12 * A20;
        float N11 = R10 * A01 + R11 * A11 + R12 * A21;
        float N12 = R10 * A02 + R11 * A12 + R12 * A22;
        float N20 = R20 * A00 + R21 * A10 + R22 * A20;
        float N21 = R20 * A01 + R21 * A11 + R22 * A21;
        float N22 = R20 * A02 + R21 * A12 + R22 * A22;
        R00 = N00; R01 = N01; R02 = N02;
        R10 = N10; R11 = N11; R12 = N12;
        R20 = N20; R21 = N21; R22 = N22;
    }
}

extern "C" void kernel_launch(void* const* d_in, const int* in_sizes, int n_in,
                              void* d_out, int out_size, void* d_ws, size_t ws_size,
                              hipStream_t stream) {
    const float* z_grid       = (const float*)d_in[0];
    const float* friction     = (const float*)d_in[1];
    const float* controls     = (const float*)d_in[2];
    const float* robot_points = (const float*)d_in[3];
    const float* x0           = (const float*)d_in[4];
    const float* xd0          = (const float*)d_in[5];
    const float* R0           = (const float*)d_in[6];
    const float* omega0       = (const float*)d_in[7];
    int B = in_sizes[4] / 3;                 // 64
    int T = in_sizes[2] / (B * 2);           // 500
    size_t need = (size_t)B * GH * GW * sizeof(float) * 4;
    if (ws_size >= need) {
        prep_kernel<<<dim3(GH, B), GW, 0, stream>>>(z_grid, friction, (f4*)d_ws);
        dphys_kernel<<<B, 128, 0, stream>>>((const f4*)d_ws, controls, robot_points,
                                            x0, xd0, R0, omega0, (float*)d_out, T);
    } else {
        dphys_kernel_fb<<<B, 128, 0, stream>>>(z_grid, friction, controls, robot_points,
                                               x0, xd0, R0, omega0, (float*)d_out, T);
    }
}